// Round 4
// baseline (210.796 us; speedup 1.0000x reference)
//
#include <hip/hip_runtime.h>
#include <hip/hip_bf16.h>

#define NN 4096
#define LOG2E 1.44269504088896340736f
#define SPLITS 8

typedef __attribute__((ext_vector_type(8))) short s8v;   // 8 x bf16
typedef __attribute__((ext_vector_type(4))) float f4v;   // mfma accumulator

__device__ __forceinline__ unsigned fu(float x){ union{float f;unsigned u;}z; z.f=x; return z.u; }
// pack two floats to bf16x2 by truncation (bias cancels in acc/l ratio)
__device__ __forceinline__ unsigned pack2(float a, float b){
  return __builtin_amdgcn_perm(fu(b), fu(a), 0x07060302u);
}
__device__ __forceinline__ unsigned short f2bf_rne(float x){
  unsigned u = fu(x);
  u += 0x7fffu + ((u >> 16) & 1u);
  return (unsigned short)(u >> 16);
}

// Kernel 1: h = x@W (fp32), write Vt[c][j] (bf16, transposed),
// el' (x LOG2E) and factorized exponentials Qr=exp2(er'), Sr=exp2(0.2*er').
__global__ __launch_bounds__(256) void k1_proj(
    const float* __restrict__ x, const float* __restrict__ W,
    const float* __restrict__ a, unsigned short* __restrict__ Vt,
    float* __restrict__ el4, float* __restrict__ Qr, float* __restrict__ Sr)
{
  __shared__ float4 xs[512];           // 8 rows x 256 cols fp32
  const int t = threadIdx.x;
  const int r0 = blockIdx.x * 8;
  const float4* xg = (const float4*)(x + (size_t)r0 * 256);
  xs[t] = xg[t];
  xs[t + 256] = xg[t + 256];
  __syncthreads();

  float acc[8] = {0.f,0.f,0.f,0.f,0.f,0.f,0.f,0.f};
  const float* Wp = W + t;             // column c = t
  float w0 = Wp[0], w1 = Wp[256], w2 = Wp[512], w3 = Wp[768];
  #pragma unroll 1
  for (int k4 = 0; k4 < 64; ++k4) {
    const int kn = (k4 + 1) & 63;      // wrap: last prefetch reads valid memory
    float nw0 = Wp[kn*1024 +   0];
    float nw1 = Wp[kn*1024 + 256];
    float nw2 = Wp[kn*1024 + 512];
    float nw3 = Wp[kn*1024 + 768];
    #pragma unroll
    for (int r = 0; r < 8; ++r) {
      float4 xv = xs[r*64 + k4];       // broadcast LDS read
      acc[r] = fmaf(xv.x, w0, acc[r]);
      acc[r] = fmaf(xv.y, w1, acc[r]);
      acc[r] = fmaf(xv.z, w2, acc[r]);
      acc[r] = fmaf(xv.w, w3, acc[r]);
    }
    w0 = nw0; w1 = nw1; w2 = nw2; w3 = nw3;
  }

  // Vt write: thread t holds 8 consecutive-j values of column c=t -> one 16B store
  union { unsigned u[4]; s8v v; } pk;
  #pragma unroll
  for (int p = 0; p < 4; ++p)
    pk.u[p] = (unsigned)f2bf_rne(acc[2*p]) | ((unsigned)f2bf_rne(acc[2*p+1]) << 16);
  *(s8v*)(Vt + (size_t)t * NN + r0) = pk.v;

  // el/er: wave w == head h; lane f = t&63
  const int f = t & 63, h = t >> 6;
  const float al = a[f], ar = a[64 + f];
  #pragma unroll
  for (int r = 0; r < 8; ++r) {
    float v = acc[r] * al;
    float u = acc[r] * ar;
    #pragma unroll
    for (int off = 32; off > 0; off >>= 1) {
      v += __shfl_xor(v, off);
      u += __shfl_xor(u, off);
    }
    if (f == 0) {
      el4[(r0 + r) * 4 + h] = v * LOG2E;                     // [i][h] (x LOG2E)
      float up = u * LOG2E;
      Qr[h * NN + (r0 + r)] = __builtin_amdgcn_exp2f(up);        // [h][j]
      Sr[h * NN + (r0 + r)] = __builtin_amdgcn_exp2f(0.2f * up); // [h][j]
    }
  }
}

// Kernel 2: fused mask+lrelu+exp (factorized) + PV GEMM via MFMA.
// grid (128 i-tiles of 32 rows, SPLITS j-chunks of 512), block 256 = 4 waves.
// wave w: i-subtile sub = w&1 (16 rows), j-half = w>>1 (256 of the 512 chunk).
// Q/S staged in LDS; adj prefetch depth 2; Vt B-frags pipelined one h ahead.
// lane: m = l&15 (row), q = l>>4 (k-quad).
__global__ __launch_bounds__(256, 3) void k2_attn(
    const float* __restrict__ adj, const unsigned short* __restrict__ Vt,
    const float* __restrict__ el4, const float* __restrict__ Qr,
    const float* __restrict__ Sr, float* __restrict__ accP,
    float* __restrict__ lP)
{
  // union: [0,5120) = Q/S staging (4h x 16 jg x 4 q x 20: {Q[8],S[8]} pad 4)
  //        whole    = cross-wave merge buffer (2 x 64 lanes x 64 acc, stride 68)
  __shared__ float shmem[128 * 68];
  const int t = threadIdx.x;
  const int w = t >> 6, l = t & 63;
  const int m = l & 15, q = l >> 4;
  const int sub = w & 1, half = w >> 1;
  const int i0 = blockIdx.x * 32;
  const int split = blockIdx.y;
  const int i = i0 + sub * 16 + m;
  const int jwin = split * 512;

  // ---- stage Q/S for the block's 512-j window into LDS ----
  {
    const int f = t & 127, isS = t >> 7;
    const int jg = f >> 3, qq = (f >> 1) & 3, pos = (f & 1) * 4;
    const float* src = isS ? Sr : Qr;
    #pragma unroll
    for (int h = 0; h < 4; ++h) {
      float4 v = *(const float4*)(src + h * NN + jwin + f * 4);
      *(float4*)(shmem + ((h * 16 + jg) * 4 + qq) * 20 + isS * 8 + pos) = v;
    }
  }

  float4 elv = *(const float4*)(el4 + i * 4);
  const float P[4] = { __builtin_amdgcn_exp2f(elv.x), __builtin_amdgcn_exp2f(elv.y),
                       __builtin_amdgcn_exp2f(elv.z), __builtin_amdgcn_exp2f(elv.w) };
  const float R[4] = { __builtin_amdgcn_exp2f(0.2f*elv.x), __builtin_amdgcn_exp2f(0.2f*elv.y),
                       __builtin_amdgcn_exp2f(0.2f*elv.z), __builtin_amdgcn_exp2f(0.2f*elv.w) };

  f4v acc[4][4];
  #pragma unroll
  for (int h = 0; h < 4; ++h)
    #pragma unroll
    for (int nf = 0; nf < 4; ++nf)
      acc[h][nf] = (f4v){0.f, 0.f, 0.f, 0.f};
  f4v accL[4] = {(f4v){0.f,0.f,0.f,0.f},(f4v){0.f,0.f,0.f,0.f},
                 (f4v){0.f,0.f,0.f,0.f},(f4v){0.f,0.f,0.f,0.f}};

  union { unsigned u[4]; s8v v; } ones;   // all-ones bf16 B: row-sum trick for l
  #pragma unroll
  for (int p = 0; p < 4; ++p) ones.u[p] = 0x3F803F80u;

  const float* arow = adj + (size_t)i * NN;
  const int jbase = jwin + half * 256 + q * 8;

  // adj pipeline: depth 2
  float4 aA0 = *(const float4*)(arow + jbase);
  float4 aA1 = *(const float4*)(arow + jbase + 4);
  float4 aB0 = *(const float4*)(arow + jbase + 32);
  float4 aB1 = *(const float4*)(arow + jbase + 36);

  // B-frag pipeline: preload (jc=0, h=0)
  s8v Bc[4];
  #pragma unroll
  for (int nf = 0; nf < 4; ++nf)
    Bc[nf] = *(const s8v*)(Vt + (size_t)(nf * 16 + m) * NN + jbase);

  __syncthreads();   // qs staged

  int j0 = jbase;
  #pragma unroll 1
  for (int jc = 0; jc < 8; ++jc) {
    const int jn2 = (jc < 6) ? (j0 + 64) : jbase;   // depth-2 prefetch, guarded
    float4 aC0 = *(const float4*)(arow + jn2);
    float4 aC1 = *(const float4*)(arow + jn2 + 4);
    const int jnext = (jc < 7) ? (j0 + 32) : jbase;

    #pragma unroll
    for (int h = 0; h < 4; ++h) {
      // prefetch next (h+1, same jc) or (h=0, next jc) B-frags
      const int hn = (h < 3) ? h + 1 : 0;
      const int jB = (h < 3) ? j0 : jnext;
      s8v Bn[4];
      #pragma unroll
      for (int nf = 0; nf < 4; ++nf)
        Bn[nf] = *(const s8v*)(Vt + (size_t)(hn * 64 + nf * 16 + m) * NN + jB);

      const int jg = half * 8 + jc;
      const float* qs = shmem + ((h * 16 + jg) * 4 + q) * 20;
      float4 q0  = *(const float4*)(qs);
      float4 q1  = *(const float4*)(qs + 4);
      float4 sv0 = *(const float4*)(qs + 8);
      float4 sv1 = *(const float4*)(qs + 12);
      const float Ph = P[h], Rh = R[h];
      float s0 = aA0.x * fmaxf(Ph * q0.x, Rh * sv0.x);
      float s1 = aA0.y * fmaxf(Ph * q0.y, Rh * sv0.y);
      float s2 = aA0.z * fmaxf(Ph * q0.z, Rh * sv0.z);
      float s3 = aA0.w * fmaxf(Ph * q0.w, Rh * sv0.w);
      float s4 = aA1.x * fmaxf(Ph * q1.x, Rh * sv1.x);
      float s5 = aA1.y * fmaxf(Ph * q1.y, Rh * sv1.y);
      float s6 = aA1.z * fmaxf(Ph * q1.z, Rh * sv1.z);
      float s7 = aA1.w * fmaxf(Ph * q1.w, Rh * sv1.w);
      union { unsigned u[4]; s8v v; } A;   // A-frag: row m, k = q*8+idx
      A.u[0] = pack2(s0, s1);
      A.u[1] = pack2(s2, s3);
      A.u[2] = pack2(s4, s5);
      A.u[3] = pack2(s6, s7);
      #pragma unroll
      for (int nf = 0; nf < 4; ++nf)
        acc[h][nf] = __builtin_amdgcn_mfma_f32_16x16x32_bf16(A.v, Bc[nf], acc[h][nf], 0, 0, 0);
      accL[h] = __builtin_amdgcn_mfma_f32_16x16x32_bf16(A.v, ones.v, accL[h], 0, 0, 0);
      #pragma unroll
      for (int nf = 0; nf < 4; ++nf) Bc[nf] = Bn[nf];   // h-loop unrolled: free rename
    }
    j0 += 32;
    aA0 = aB0; aA1 = aB1; aB0 = aC0; aB1 = aC1;
  }

  // l partials per (split, half); C/D layout: col = m, row = q*4 + r
  if (m == 0) {
    #pragma unroll
    for (int h = 0; h < 4; ++h)
      #pragma unroll
      for (int r = 0; r < 4; ++r) {
        int row = i0 + sub * 16 + q * 4 + r;
        lP[((size_t)(split * 2 + half) * NN + row) * 4 + h] = accL[h][r];
      }
  }

  __syncthreads();   // all qs reads done before merge buffer aliases it
  if (w >= 2) {
    const int base = ((w - 2) * 64 + l) * 68;
    #pragma unroll
    for (int h = 0; h < 4; ++h)
      #pragma unroll
      for (int nf = 0; nf < 4; ++nf)
        *(f4v*)(shmem + base + h * 16 + nf * 4) = acc[h][nf];
  }
  __syncthreads();
  if (w < 2) {
    const int base = (w * 64 + l) * 68;
    float* ap = accP + (size_t)split * NN * 256;
    #pragma unroll
    for (int h = 0; h < 4; ++h)
      #pragma unroll
      for (int nf = 0; nf < 4; ++nf) {
        f4v other = *(const f4v*)(shmem + base + h * 16 + nf * 4);
        f4v s = acc[h][nf] + other;
        #pragma unroll
        for (int r = 0; r < 4; ++r) {
          int row = i0 + sub * 16 + q * 4 + r;
          int col = h * 64 + nf * 16 + m;
          ap[(size_t)row * 256 + col] = s[r];
        }
      }
  }
}

// Kernel 3: combine split partials, divide by l, mean over heads.
__global__ __launch_bounds__(256) void k3_reduce(
    const float* __restrict__ accP, const float* __restrict__ lP,
    float* __restrict__ out)
{
  int tid = blockIdx.x * 256 + threadIdx.x;  // 262144 threads
  int i = tid >> 6, f = tid & 63;
  float o = 0.f;
  #pragma unroll
  for (int h = 0; h < 4; ++h) {
    float sa = 0.f, sl = 0.f;
    #pragma unroll
    for (int s = 0; s < SPLITS; ++s)
      sa += accP[((size_t)s * NN + i) * 256 + h * 64 + f];
    #pragma unroll
    for (int s = 0; s < 2 * SPLITS; ++s)
      sl += lP[((size_t)s * NN + i) * 4 + h];
    o += sa / sl;   // sl > 0 guaranteed: diagonal of adj is 1
  }
  out[tid] = 0.25f * o;
}

extern "C" void kernel_launch(void* const* d_in, const int* in_sizes, int n_in,
                              void* d_out, int out_size, void* d_ws, size_t ws_size,
                              hipStream_t stream) {
  const float* x   = (const float*)d_in[0];   // (4096, 256)
  const float* adj = (const float*)d_in[1];   // (4096, 4096)
  const float* W   = (const float*)d_in[2];   // (256, 256)
  const float* a   = (const float*)d_in[3];   // (128, 1)
  float* out = (float*)d_out;                 // (4096, 64)

  char* ws = (char*)d_ws;
  unsigned short* Vt = (unsigned short*)ws;                       // 2 MB  bf16 [256][4096]
  float* el4 = (float*)(ws + (2u << 20));                         // 64 KB [4096][4]
  float* Qr  = (float*)(ws + (2u << 20) + (64u << 10));           // 64 KB [4][4096]
  float* Sr  = (float*)(ws + (2u << 20) + (128u << 10));          // 64 KB [4][4096]
  float* lP  = (float*)(ws + (2u << 20) + (192u << 10));          // 1 MB  [16][4096][4]
  float* accP= (float*)(ws + (3u << 20) + (192u << 10));          // 32 MB [8][4096][256]

  k1_proj<<<512, 256, 0, stream>>>(x, W, a, Vt, el4, Qr, Sr);
  k2_attn<<<dim3(128, SPLITS), 256, 0, stream>>>(adj, Vt, el4, Qr, Sr, accP, lP);
  k3_reduce<<<1024, 256, 0, stream>>>(accP, lP, out);
}